// Round 4
// baseline (10159.952 us; speedup 1.0000x reference)
//
#include <hip/hip_runtime.h>
#include <hip/hip_bf16.h>
#include <hip/hip_fp16.h>
#include <stdint.h>

typedef short bf16x8 __attribute__((ext_vector_type(8)));
typedef float f32x4  __attribute__((ext_vector_type(4)));
typedef __hip_bfloat16 bf16;

#define MFMA16(a,b,c) __builtin_amdgcn_mfma_f32_16x16x32_bf16((a),(b),(c),0,0,0)

__device__ __forceinline__ float bf2f(bf16 x){ return __bfloat162float(x); }
__device__ __forceinline__ bf16  f2bf(float x){ return __float2bfloat16(x); }
// sanitize: kill NaN/inf (NaN compares false -> 0)
__device__ __forceinline__ float sf(float x){ return (fabsf(x) < 1e30f) ? x : 0.f; }

// Problem: B=128, L=256, H=512, OUT=256. All I/O float32. Chunked: 8 x 32 steps.
#define NB   128
#define NL   256
#define CH   32     // steps per chunk
#define MCH  4096   // rows per chunk = CH*NB
#define NQ   8      // chunks

// ---------------- weight preprocessing (f32 in -> bf16 internal) ----------------

// WcatT[n][k] (1536 x 1024): [Wx;Wm]^T, k-contiguous
__global__ void build_wcatT(const float* __restrict__ Wx, const float* __restrict__ Wm,
                            bf16* __restrict__ dst) {
    int i = blockIdx.x * 256 + threadIdx.x;
    if (i >= 1536 * 1024) return;
    int n = i >> 10, k = i & 1023;
    float v = (k < 512) ? Wx[k * 1536 + n] : Wm[(k - 512) * 1536 + n];
    dst[i] = f2bf(sf(v));
}

// transpose: src (R x C) f32 -> dst (C x R) bf16
__global__ void transpose_f2b(const float* __restrict__ src, bf16* __restrict__ dst,
                              int R, int C) {
    int i = blockIdx.x * 256 + threadIdx.x;
    if (i >= R * C) return;
    int r = i % R, c = i / R;
    dst[i] = f2bf(sf(src[r * C + c]));
}

// ---------------- x-path (h-independent) ----------------

__global__ void xmean_kernel(const int* __restrict__ mask, const float* __restrict__ Cmat,
                             float* __restrict__ xmean) {
    int g = blockIdx.x * 256 + threadIdx.x;   // 65536 threads: (b,h)
    int b = g >> 9, h = g & 511;
    float s = 0.f, cnt = 0.f;
    for (int l = 0; l < NL; ++l) {
        int m = mask[(size_t)((b << 8) + l) * 512 + h];
        if (m) { s += sf(Cmat[(l << 9) + h]); cnt += 1.f; }
    }
    xmean[g] = s / fmaxf(cnt, 1.f);
}

// chunked elementwise recurrence: delta, gamma_x, x_hat, x_last; carries in global
__global__ void prep_kernel(const int* __restrict__ mask, const float* __restrict__ Cmat,
                            const float* __restrict__ t_in,
                            const float* __restrict__ w_gx, const float* __restrict__ b_gx,
                            const float* __restrict__ xmean,
                            float* __restrict__ xlastC, float* __restrict__ dprevC,
                            float* __restrict__ mprevC, float* __restrict__ tprevC,
                            bf16* __restrict__ Xcat,   // (4096,1024) l-major: [x_hat|m]
                            bf16* __restrict__ Dbuf,   // (4096,512) l-major: delta
                            int q) {
    int g = blockIdx.x * 256 + threadIdx.x;
    int b = g >> 9, h = g & 511;
    float wg = sf(w_gx[h]), bg = sf(b_gx[h]);
    float xm = xmean[g];
    float xlast, dprev, mprev, tprev;
    if (q == 0) { xlast = xm; dprev = 0.f; mprev = 1.f; tprev = 0.f; }
    else { xlast = xlastC[g]; dprev = dprevC[g]; mprev = mprevC[g]; tprev = tprevC[g]; }
    for (int ll = 0; ll < CH; ++ll) {
        int l = q * CH + ll;
        float tc = sf(t_in[(b << 8) + l]);
        float dtv = (l == 0) ? 0.f : (tc - tprev);
        tprev = tc;
        float mi = (float)mask[(size_t)((b << 8) + l) * 512 + h];
        float delta = dtv + (1.f - mprev) * dprev;
        float gx = __expf(-fmaxf(wg * delta + bg, 0.f));
        float xi = sf(Cmat[(l << 9) + h]);
        float xh = mi * xi + (1.f - mi) * (gx * xlast + (1.f - gx) * xm);
        size_t row = (size_t)ll * 128 + b;           // l-major chunk row
        Xcat[row * 1024 + h]       = f2bf(xh);
        Xcat[row * 1024 + 512 + h] = f2bf(mi);
        Dbuf[row * 512 + h]        = f2bf(delta);
        xlast = mi * xi + (1.f - mi) * xlast;
        dprev = delta; mprev = mi;
    }
    xlastC[g] = xlast; dprevC[g] = dprev; mprevC[g] = mprev; tprevC[g] = tprev;
}

// ---------------- tiled MFMA GEMM, A (MxK) row-major bf16, BT (NxK) row-major bf16 ----
// MODE 0: bf16 out = acc+bias ; MODE 1: fp16 out = exp(-relu(acc+bias)) ;
// MODE 2: f32 out = acc+bias with chunk-row remap (l-major -> (b,l))
template <int MODE>
__global__ __launch_bounds__(256) void gemm_bt(const bf16* __restrict__ A,
                                               const bf16* __restrict__ BT,
                                               const float* __restrict__ bias,
                                               void* __restrict__ Cout,
                                               int N, int K, int q) {
    const int nb = N >> 7;
    int bn = blockIdx.x % nb, bm = blockIdx.x / nb;
    __shared__ bf16 As[4096];   // [kc][row] 16B chunks
    __shared__ bf16 Bs[4096];
    int tid = threadIdx.x, lane = tid & 63, w = tid >> 6;
    int wm = w >> 1, wn = w & 1;
    int quad = lane >> 4, l15 = lane & 15;
    f32x4 acc[4][4];
    #pragma unroll
    for (int i = 0; i < 4; ++i)
        #pragma unroll
        for (int j = 0; j < 4; ++j) acc[i][j] = (f32x4){0.f, 0.f, 0.f, 0.f};

    for (int k0 = 0; k0 < K; k0 += 32) {
        bf16x8 av[2], bv[2];
        #pragma unroll
        for (int cc = 0; cc < 2; ++cc) {
            int c = tid + cc * 256;
            int row = c >> 2, kc = c & 3;
            av[cc] = *(const bf16x8*)(A  + (size_t)(bm * 128 + row) * K + k0 + kc * 8);
            bv[cc] = *(const bf16x8*)(BT + (size_t)(bn * 128 + row) * K + k0 + kc * 8);
        }
        __syncthreads();
        #pragma unroll
        for (int cc = 0; cc < 2; ++cc) {
            int c = tid + cc * 256;
            int row = c >> 2, kc = c & 3;
            *(bf16x8*)&As[(kc * 128 + row) * 8] = av[cc];
            *(bf16x8*)&Bs[(kc * 128 + row) * 8] = bv[cc];
        }
        __syncthreads();
        bf16x8 af[4], bfr[4];
        #pragma unroll
        for (int mt = 0; mt < 4; ++mt)
            af[mt] = *(const bf16x8*)&As[(quad * 128 + wm * 64 + mt * 16 + l15) * 8];
        #pragma unroll
        for (int nt = 0; nt < 4; ++nt)
            bfr[nt] = *(const bf16x8*)&Bs[(quad * 128 + wn * 64 + nt * 16 + l15) * 8];
        #pragma unroll
        for (int mt = 0; mt < 4; ++mt)
            #pragma unroll
            for (int nt = 0; nt < 4; ++nt)
                acc[mt][nt] = MFMA16(af[mt], bfr[nt], acc[mt][nt]);
    }
    int row0 = bm * 128 + wm * 64, col0 = bn * 128 + wn * 64;
    #pragma unroll
    for (int mt = 0; mt < 4; ++mt) {
        #pragma unroll
        for (int nt = 0; nt < 4; ++nt) {
            int col = col0 + nt * 16 + l15;
            float bvf = sf(bias[col]);
            #pragma unroll
            for (int r = 0; r < 4; ++r) {
                int row = row0 + mt * 16 + quad * 4 + r;
                float v = acc[mt][nt][r] + bvf;
                if (MODE == 1)
                    ((__half*)Cout)[(size_t)row * N + col] = __float2half(__expf(-fmaxf(v, 0.f)));
                else if (MODE == 2) {
                    int bb = row & 127, lloc = row >> 7;
                    ((float*)Cout)[(size_t)((bb << 8) + q * CH + lloc) * N + col] = v;
                } else
                    ((bf16*)Cout)[(size_t)row * N + col] = f2bf(v);
            }
        }
    }
}

// ---------------- sequential h-scan over one 32-step chunk ----------------
// grid = 64 blocks: 8 clusters (16 batch rows) x 8 WGs. Wave wi in [0,32):
// zr cols [wi*32,wi*32+32), ht col 1024+[wi*16,wi*16+16). Wh slices register-stationary.
__global__ __launch_bounds__(256, 1) void scan_kernel(
        const bf16* __restrict__ pre,      // (4096,1536) l-major
        const __half* __restrict__ gammaf, // (4096,512) l-major
        const bf16* __restrict__ WhT,      // (1536,512)
        bf16* __restrict__ hseq,           // (4096,512) l-major
        float* __restrict__ hcarry,        // (128,512)
        float* __restrict__ zrbuf,         // [2][8][16][1024]
        float* __restrict__ htbuf,         // [8][16][512]
        unsigned* __restrict__ ctr) {      // this chunk's slot (512 uints, zeroed)
    int bx = blockIdx.x;
    int c = bx >> 3, w = bx & 7;
    int tid = threadIdx.x, lane = tid & 63, v = tid >> 6;
    int wi = (w << 2) | v;                 // 0..31
    int quad = lane >> 4, l15 = lane & 15;
    __shared__ float hf[16 * 512];
    __shared__ bf16  hb[16 * 520];
    __shared__ bf16  rh[16 * 520];

    // stationary Wh B-fragments: B[n=l15][k=quad*8+j], per kf block of K=32
    bf16x8 whzr[2][16], whht[16];
    int zcol0 = wi * 32;
    #pragma unroll
    for (int tt = 0; tt < 2; ++tt)
        #pragma unroll
        for (int kf = 0; kf < 16; ++kf) {
            int n = zcol0 + tt * 16 + l15;
            whzr[tt][kf] = *(const bf16x8*)(WhT + (size_t)n * 512 + kf * 32 + quad * 8);
        }
    #pragma unroll
    for (int kf = 0; kf < 16; ++kf) {
        int n = 1024 + wi * 16 + l15;
        whht[kf] = *(const bf16x8*)(WhT + (size_t)n * 512 + kf * 32 + quad * 8);
    }

    // init h = hcarry * gamma(local step 0)
    for (int i = tid; i < 16 * 512; i += 256) {
        int row = i >> 9, col = i & 511;
        int brow = c * 16 + row;
        float g0 = __half2float(gammaf[(size_t)brow * 512 + col]);
        float h0 = hcarry[(size_t)brow * 512 + col] * g0;
        hf[i] = h0;
        hb[row * 520 + col] = f2bf(h0);
    }
    __syncthreads();

    unsigned* ctrA = ctr + c * 32;
    unsigned* ctrB = ctrA + 16;

    for (int t = 0; t < CH; ++t) {
        // ---- phase A: zr = sigmoid(pre12 + h @ Wh[:, :1024]) ----
        f32x4 acc0 = (f32x4){0.f,0.f,0.f,0.f}, acc1 = acc0;
        #pragma unroll
        for (int kf = 0; kf < 16; ++kf) {
            bf16x8 a = *(const bf16x8*)&hb[l15 * 520 + kf * 32 + quad * 8];
            acc0 = MFMA16(a, whzr[0][kf], acc0);
            acc1 = MFMA16(a, whzr[1][kf], acc1);
        }
        float* zrw = zrbuf + (size_t)(t & 1) * (8 * 16 * 1024) + (size_t)c * 16 * 1024;
        #pragma unroll
        for (int r = 0; r < 4; ++r) {
            int row = quad * 4 + r;
            int brow = c * 16 + row;
            size_t prow = ((size_t)t * 128 + brow) * 1536;
            int col0 = zcol0 + l15;
            float x0 = acc0[r] + bf2f(pre[prow + col0]);
            zrw[row * 1024 + col0] = 1.f / (1.f + __expf(-x0));
            int col1 = zcol0 + 16 + l15;
            float x1 = acc1[r] + bf2f(pre[prow + col1]);
            zrw[row * 1024 + col1] = 1.f / (1.f + __expf(-x1));
        }
        __syncthreads();
        if (tid == 0) {
            __threadfence();
            __hip_atomic_fetch_add(ctrA, 1u, __ATOMIC_RELEASE, __HIP_MEMORY_SCOPE_AGENT);
            unsigned tgt = 8u * (t + 1);
            int guard = 0;
            while (__hip_atomic_load(ctrA, __ATOMIC_ACQUIRE, __HIP_MEMORY_SCOPE_AGENT) < tgt
                   && ++guard < (1 << 16))
                __builtin_amdgcn_s_sleep(1);
            __threadfence();
        }
        __syncthreads();
        // ---- phase B: h_tilde = tanh(pre3 + (r*h) @ Wh[:, 1024:]) ----
        for (int i = tid; i < 16 * 512; i += 256) {
            int row = i >> 9, col = i & 511;
            float rv = zrw[row * 1024 + 512 + col];
            rh[row * 520 + col] = f2bf(rv * hf[row * 512 + col]);
        }
        __syncthreads();
        f32x4 acch = (f32x4){0.f,0.f,0.f,0.f};
        #pragma unroll
        for (int kf = 0; kf < 16; ++kf) {
            bf16x8 a = *(const bf16x8*)&rh[l15 * 520 + kf * 32 + quad * 8];
            acch = MFMA16(a, whht[kf], acch);
        }
        float* htw = htbuf + (size_t)c * 16 * 512;
        #pragma unroll
        for (int r = 0; r < 4; ++r) {
            int row = quad * 4 + r;
            int brow = c * 16 + row;
            int colh = wi * 16 + l15;
            float x = acch[r] + bf2f(pre[((size_t)t * 128 + brow) * 1536 + 1024 + colh]);
            float e = __expf(-2.f * fabsf(x));
            float th = (1.f - e) / (1.f + e);
            htw[row * 512 + colh] = copysignf(th, x);
        }
        __syncthreads();
        if (tid == 0) {
            __threadfence();
            __hip_atomic_fetch_add(ctrB, 1u, __ATOMIC_RELEASE, __HIP_MEMORY_SCOPE_AGENT);
            unsigned tgt = 8u * (t + 1);
            int guard = 0;
            while (__hip_atomic_load(ctrB, __ATOMIC_ACQUIRE, __HIP_MEMORY_SCOPE_AGENT) < tgt
                   && ++guard < (1 << 16))
                __builtin_amdgcn_s_sleep(1);
            __threadfence();
        }
        __syncthreads();
        // ---- phase C: h_new = (1-z)h + z*h_tilde ; apply gamma(t+1) in-chunk ----
        for (int i = tid; i < 16 * 512; i += 256) {
            int row = i >> 9, col = i & 511;
            float z  = zrw[row * 1024 + col];
            float ht = htw[row * 512 + col];
            float hd = hf[row * 512 + col];
            float hn = (1.f - z) * hd + z * ht;
            int brow = c * 16 + row;
            if (w == 0) hseq[((size_t)t * 128 + brow) * 512 + col] = f2bf(hn);
            float hnext;
            if (t < CH - 1) {
                hnext = hn * __half2float(gammaf[((size_t)(t + 1) * 128 + brow) * 512 + col]);
            } else {
                if (w == 0) hcarry[(size_t)brow * 512 + col] = hn;   // raw carry
                hnext = hn;
            }
            hf[row * 512 + col] = hnext;
            hb[row * 520 + col] = f2bf(hnext);
        }
        __syncthreads();
    }
}

// ---------------- launcher ----------------

extern "C" void kernel_launch(void* const* d_in, const int* in_sizes, int n_in,
                              void* d_out, int out_size, void* d_ws, size_t ws_size,
                              hipStream_t stream) {
    const float* C     = (const float*)d_in[0];
    const float* t_in  = (const float*)d_in[1];
    const int*   mask  = (const int*)d_in[2];
    const float* Wx    = (const float*)d_in[3];
    const float* Wh    = (const float*)d_in[4];
    const float* Wm    = (const float*)d_in[5];
    const float* bvec  = (const float*)d_in[6];
    const float* w_gx  = (const float*)d_in[7];
    const float* b_gx  = (const float*)d_in[8];
    const float* W_gh  = (const float*)d_in[9];
    const float* b_gh  = (const float*)d_in[10];
    const float* W_out = (const float*)d_in[11];
    const float* b_out = (const float*)d_in[12];

    char* w = (char*)d_ws;                              // total used: 41,959,424 B
    unsigned* ctr   = (unsigned*)(w + 0);               //   16384 (8 chunk slots)
    float* hcarry   = (float*)(w + 16384);              //  262144
    float* xmean    = (float*)(w + 278528);             //  262144
    float* xlastC   = (float*)(w + 540672);             //  262144
    float* dprevC   = (float*)(w + 802816);             //  262144
    float* mprevC   = (float*)(w + 1064960);            //  262144
    float* tprevC   = (float*)(w + 1327104);            //  262144
    bf16*  wcatT    = (bf16*)(w + 1589248);             // 3145728
    bf16*  wghT     = (bf16*)(w + 4734976);             //  524288
    bf16*  whT      = (bf16*)(w + 5259264);             // 1572864
    bf16*  woutT    = (bf16*)(w + 6832128);             //  262144
    bf16*  Xcat     = (bf16*)(w + 7094272);             //  8388608 (chunk)
    bf16*  Dbuf     = (bf16*)(w + 15482880);            //  4194304 (chunk)
    bf16*  pre      = (bf16*)(w + 19677184);            // 12582912 (chunk)
    __half* gamma   = (__half*)(w + 32260096);          //  4194304 (chunk)
    bf16*  hseq     = (bf16*)(w + 36454400);            //  4194304 (chunk)
    float* zrbuf    = (float*)(w + 40648704);           //  1048576
    float* htbuf    = (float*)(w + 41697280);           //   262144

    hipMemsetAsync(w, 0, 278528, stream);               // ctr + hcarry

    build_wcatT<<<6144, 256, 0, stream>>>(Wx, Wm, wcatT);
    transpose_f2b<<<1024, 256, 0, stream>>>(W_gh, wghT, 512, 512);
    transpose_f2b<<<3072, 256, 0, stream>>>(Wh, whT, 512, 1536);
    transpose_f2b<<<512, 256, 0, stream>>>(W_out, woutT, 512, 256);
    xmean_kernel<<<256, 256, 0, stream>>>(mask, C, xmean);

    for (int q = 0; q < NQ; ++q) {
        prep_kernel<<<256, 256, 0, stream>>>(mask, C, t_in, w_gx, b_gx, xmean,
                                             xlastC, dprevC, mprevC, tprevC,
                                             Xcat, Dbuf, q);
        gemm_bt<0><<<32 * 12, 256, 0, stream>>>(Xcat, wcatT, bvec, (void*)pre, 1536, 1024, q);
        gemm_bt<1><<<32 * 4, 256, 0, stream>>>(Dbuf, wghT, b_gh, (void*)gamma, 512, 512, q);
        scan_kernel<<<64, 256, 0, stream>>>(pre, gamma, whT, hseq, hcarry,
                                            zrbuf, htbuf, ctr + q * 512);
        gemm_bt<2><<<32 * 2, 256, 0, stream>>>(hseq, woutT, b_out, d_out, 256, 512, q);
    }
}

// Round 5
// 4299.112 us; speedup vs baseline: 2.3633x; 2.3633x over previous
//
#include <hip/hip_runtime.h>
#include <hip/hip_bf16.h>
#include <hip/hip_fp16.h>
#include <stdint.h>

typedef short bf16x8 __attribute__((ext_vector_type(8)));
typedef short short4v __attribute__((ext_vector_type(4)));
typedef unsigned short ushort4v __attribute__((ext_vector_type(4)));
typedef float f32x4  __attribute__((ext_vector_type(4)));
typedef __hip_bfloat16 bf16;

#define MFMA16(a,b,c) __builtin_amdgcn_mfma_f32_16x16x32_bf16((a),(b),(c),0,0,0)

__device__ __forceinline__ float bf2f(bf16 x){ return __bfloat162float(x); }
__device__ __forceinline__ bf16  f2bf(float x){ return __float2bfloat16(x); }
__device__ __forceinline__ short f2bs(float x){ bf16 t = __float2bfloat16(x); return *(short*)&t; }
__device__ __forceinline__ float bs2f(short s){ bf16 t; *(short*)&t = s; return __bfloat162float(t); }
// sanitize raw f32 inputs: kill NaN/inf
__device__ __forceinline__ float sf(float x){ return (fabsf(x) < 1e30f) ? x : 0.f; }

// Problem: B=128, L=256, H=512, OUT=256. All I/O float32. Chunked: 8 x 32 steps.
#define NB   128
#define NL   256
#define CH   32     // steps per chunk
#define MCH  4096   // rows per chunk = CH*NB
#define NQ   8      // chunks

// ---------------- weight preprocessing (f32 in -> bf16 internal) ----------------

__global__ void build_wcatT(const float* __restrict__ Wx, const float* __restrict__ Wm,
                            bf16* __restrict__ dst) {
    int i = blockIdx.x * 256 + threadIdx.x;
    if (i >= 1536 * 1024) return;
    int n = i >> 10, k = i & 1023;
    float v = (k < 512) ? Wx[k * 1536 + n] : Wm[(k - 512) * 1536 + n];
    dst[i] = f2bf(sf(v));
}

__global__ void transpose_f2b(const float* __restrict__ src, bf16* __restrict__ dst,
                              int R, int C) {
    int i = blockIdx.x * 256 + threadIdx.x;
    if (i >= R * C) return;
    int r = i % R, c = i / R;
    dst[i] = f2bf(sf(src[r * C + c]));
}

// ---------------- x-path (h-independent) ----------------

__global__ void xmean_kernel(const int* __restrict__ mask, const float* __restrict__ Cmat,
                             float* __restrict__ xmean) {
    int g = blockIdx.x * 256 + threadIdx.x;   // (b,h)
    int b = g >> 9, h = g & 511;
    float s = 0.f, cnt = 0.f;
    for (int l = 0; l < NL; ++l) {
        int m = mask[(size_t)((b << 8) + l) * 512 + h];
        if (m) { s += sf(Cmat[(l << 9) + h]); cnt += 1.f; }
    }
    xmean[g] = s / fmaxf(cnt, 1.f);
}

__global__ void prep_kernel(const int* __restrict__ mask, const float* __restrict__ Cmat,
                            const float* __restrict__ t_in,
                            const float* __restrict__ w_gx, const float* __restrict__ b_gx,
                            const float* __restrict__ xmean,
                            float* __restrict__ xlastC, float* __restrict__ dprevC,
                            float* __restrict__ mprevC, float* __restrict__ tprevC,
                            bf16* __restrict__ Xcat,   // (4096,1024) l-major: [x_hat|m]
                            bf16* __restrict__ Dbuf,   // (4096,512) l-major: delta
                            int q) {
    int g = blockIdx.x * 256 + threadIdx.x;
    int b = g >> 9, h = g & 511;
    float wg = sf(w_gx[h]), bg = sf(b_gx[h]);
    float xm = xmean[g];
    float xlast, dprev, mprev, tprev;
    if (q == 0) { xlast = xm; dprev = 0.f; mprev = 1.f; tprev = 0.f; }
    else { xlast = xlastC[g]; dprev = dprevC[g]; mprev = mprevC[g]; tprev = tprevC[g]; }
    for (int ll = 0; ll < CH; ++ll) {
        int l = q * CH + ll;
        float tc = sf(t_in[(b << 8) + l]);
        float dtv = (l == 0) ? 0.f : (tc - tprev);
        tprev = tc;
        float mi = (float)mask[(size_t)((b << 8) + l) * 512 + h];
        float delta = dtv + (1.f - mprev) * dprev;
        float gx = __expf(-fmaxf(wg * delta + bg, 0.f));
        float xi = sf(Cmat[(l << 9) + h]);
        float xh = mi * xi + (1.f - mi) * (gx * xlast + (1.f - gx) * xm);
        size_t row = (size_t)ll * 128 + b;           // l-major chunk row
        Xcat[row * 1024 + h]       = f2bf(xh);
        Xcat[row * 1024 + 512 + h] = f2bf(mi);
        Dbuf[row * 512 + h]        = f2bf(delta);
        xlast = mi * xi + (1.f - mi) * xlast;
        dprev = delta; mprev = mi;
    }
    xlastC[g] = xlast; dprevC[g] = dprev; mprevC[g] = mprev; tprevC[g] = tprev;
}

// ---------------- tiled MFMA GEMM, A (MxK) row-major bf16, BT (NxK) row-major bf16 ----
// MODE 0: bf16 out = acc+bias ; MODE 1: fp16 out = exp(-relu(acc+bias)) ;
// MODE 2: f32 out = acc+bias with chunk-row remap (l-major -> (b,l))
template <int MODE>
__global__ __launch_bounds__(256) void gemm_bt(const bf16* __restrict__ A,
                                               const bf16* __restrict__ BT,
                                               const float* __restrict__ bias,
                                               void* __restrict__ Cout,
                                               int N, int K, int q) {
    const int nb = N >> 7;
    int bn = blockIdx.x % nb, bm = blockIdx.x / nb;
    __shared__ bf16 As[4096];   // [kc][row] 16B chunks
    __shared__ bf16 Bs[4096];
    int tid = threadIdx.x, lane = tid & 63, w = tid >> 6;
    int wm = w >> 1, wn = w & 1;
    int quad = lane >> 4, l15 = lane & 15;
    f32x4 acc[4][4];
    #pragma unroll
    for (int i = 0; i < 4; ++i)
        #pragma unroll
        for (int j = 0; j < 4; ++j) acc[i][j] = (f32x4){0.f, 0.f, 0.f, 0.f};

    for (int k0 = 0; k0 < K; k0 += 32) {
        bf16x8 av[2], bv[2];
        #pragma unroll
        for (int cc = 0; cc < 2; ++cc) {
            int c = tid + cc * 256;
            int row = c >> 2, kc = c & 3;
            av[cc] = *(const bf16x8*)(A  + (size_t)(bm * 128 + row) * K + k0 + kc * 8);
            bv[cc] = *(const bf16x8*)(BT + (size_t)(bn * 128 + row) * K + k0 + kc * 8);
        }
        __syncthreads();
        #pragma unroll
        for (int cc = 0; cc < 2; ++cc) {
            int c = tid + cc * 256;
            int row = c >> 2, kc = c & 3;
            *(bf16x8*)&As[(kc * 128 + row) * 8] = av[cc];
            *(bf16x8*)&Bs[(kc * 128 + row) * 8] = bv[cc];
        }
        __syncthreads();
        bf16x8 af[4], bfr[4];
        #pragma unroll
        for (int mt = 0; mt < 4; ++mt)
            af[mt] = *(const bf16x8*)&As[(quad * 128 + wm * 64 + mt * 16 + l15) * 8];
        #pragma unroll
        for (int nt = 0; nt < 4; ++nt)
            bfr[nt] = *(const bf16x8*)&Bs[(quad * 128 + wn * 64 + nt * 16 + l15) * 8];
        #pragma unroll
        for (int mt = 0; mt < 4; ++mt)
            #pragma unroll
            for (int nt = 0; nt < 4; ++nt)
                acc[mt][nt] = MFMA16(af[mt], bfr[nt], acc[mt][nt]);
    }
    int row0 = bm * 128 + wm * 64, col0 = bn * 128 + wn * 64;
    #pragma unroll
    for (int mt = 0; mt < 4; ++mt) {
        #pragma unroll
        for (int nt = 0; nt < 4; ++nt) {
            int col = col0 + nt * 16 + l15;
            float bvf = sf(bias[col]);
            #pragma unroll
            for (int r = 0; r < 4; ++r) {
                int row = row0 + mt * 16 + quad * 4 + r;
                float v = acc[mt][nt][r] + bvf;
                if (MODE == 1)
                    ((__half*)Cout)[(size_t)row * N + col] = __float2half(__expf(-fmaxf(v, 0.f)));
                else if (MODE == 2) {
                    int bb = row & 127, lloc = row >> 7;
                    ((float*)Cout)[(size_t)((bb << 8) + q * CH + lloc) * N + col] = v;
                } else
                    ((bf16*)Cout)[(size_t)row * N + col] = f2bf(v);
            }
        }
    }
}

// ---------------- sequential h-scan over one 32-step chunk ----------------
// grid = 64 blocks: 8 clusters (16 batch rows) x 8 WGs.
// XCD-friendly mapping: cluster = bx & 7 (consecutive blockIdx round-robin XCDs,
// so a cluster's 8 WGs co-locate on one XCD — perf heuristic only).
// Wave wi in [0,32) owns the SAME 16-col slice of z, r, ht: cols wi*16..+16.
// z never leaves registers; r published after phase A; h_new published after
// phase B (z and ht co-located -> GRU update local). Phase C applies gamma.
// Sync: release fetch_add + RELAXED polls + ONE acquire fence after spin
// (acquire-per-poll invalidated L1/L2 every iteration = r4's 111MB refetch).
__global__ __launch_bounds__(256, 1) void scan_kernel(
        const bf16* __restrict__ pre,      // (4096,1536) l-major
        const __half* __restrict__ gammaf, // (4096,512) l-major
        const bf16* __restrict__ WhT,      // (1536,512)
        bf16* __restrict__ hseq,           // (4096,512) l-major
        float* __restrict__ hcarry,        // (128,512)
        float* __restrict__ rbuf,          // [8][16][512] f32
        float* __restrict__ hnbuf,         // [8][16][512] f32
        unsigned* __restrict__ ctr) {      // this chunk's slot (512 uints, zeroed)
    int bx = blockIdx.x;
    int c = bx & 7, w = bx >> 3;
    int tid = threadIdx.x, lane = tid & 63, v = tid >> 6;
    int wi = (w << 2) | v;                 // 0..31
    int quad = lane >> 4, l15 = lane & 15;
    __shared__ float hf[16 * 512];
    __shared__ bf16  hb[16 * 520];
    __shared__ bf16  rh[16 * 520];

    // stationary Wh B-fragments: B[n=l15][k=quad*8+j] per kf block of K=32
    bf16x8 whz[16], whr[16], whh[16];
    int col0 = wi * 16;                    // owned column slice (within each gate)
    #pragma unroll
    for (int kf = 0; kf < 16; ++kf) {
        int n = col0 + l15;
        whz[kf] = *(const bf16x8*)(WhT + (size_t)n * 512 + kf * 32 + quad * 8);
        whr[kf] = *(const bf16x8*)(WhT + (size_t)(512 + n) * 512 + kf * 32 + quad * 8);
        whh[kf] = *(const bf16x8*)(WhT + (size_t)(1024 + n) * 512 + kf * 32 + quad * 8);
    }

    float* rclu = rbuf  + (size_t)c * 16 * 512;
    float* hclu = hnbuf + (size_t)c * 16 * 512;

    // init h = hcarry * gamma(local step 0)
    for (int i = tid; i < 16 * 512; i += 256) {
        int row = i >> 9, col = i & 511;
        int brow = c * 16 + row;
        float g0 = __half2float(gammaf[(size_t)brow * 512 + col]);
        float h0 = hcarry[(size_t)brow * 512 + col] * g0;
        hf[i] = h0;
        hb[row * 520 + col] = f2bf(h0);
    }
    __syncthreads();

    unsigned* ctrA = ctr + c * 32;
    unsigned* ctrB = ctrA + 16;

    for (int t = 0; t < CH; ++t) {
        unsigned tgt = 8u * (t + 1);
        // ---- phase A: z (local), r (publish) ----
        f32x4 accz = (f32x4){0.f,0.f,0.f,0.f}, accr = accz;
        #pragma unroll
        for (int kf = 0; kf < 16; ++kf) {
            bf16x8 a = *(const bf16x8*)&hb[l15 * 520 + kf * 32 + quad * 8];
            accz = MFMA16(a, whz[kf], accz);
            accr = MFMA16(a, whr[kf], accr);
        }
        float zloc[4];
        #pragma unroll
        for (int r = 0; r < 4; ++r) {
            int row = quad * 4 + r;
            int brow = c * 16 + row;
            size_t prow = ((size_t)t * 128 + brow) * 1536;
            int cc = col0 + l15;
            float xz = accz[r] + bf2f(pre[prow + cc]);
            zloc[r] = 1.f / (1.f + __expf(-xz));
            float xr = accr[r] + bf2f(pre[prow + 512 + cc]);
            rclu[row * 512 + cc] = 1.f / (1.f + __expf(-xr));
        }
        __syncthreads();                      // all waves' stores drained (vmcnt)
        if (tid == 0) {
            __hip_atomic_fetch_add(ctrA, 1u, __ATOMIC_RELEASE, __HIP_MEMORY_SCOPE_AGENT);
            int guard = 0;
            while (__hip_atomic_load(ctrA, __ATOMIC_RELAXED, __HIP_MEMORY_SCOPE_AGENT) < tgt
                   && ++guard < (1 << 17))
                __builtin_amdgcn_s_sleep(1);
            __threadfence();                  // single acquire (cache inv) per sync
        }
        __syncthreads();
        // ---- phase B: rh = r*h ; ht = tanh(...); h_new local (z co-located) ----
        for (int i = tid; i < 16 * 128; i += 256) {
            int row = i >> 7, c4 = (i & 127) << 2;
            f32x4 rv = *(const f32x4*)&rclu[row * 512 + c4];
            f32x4 hv = *(const f32x4*)&hf[row * 512 + c4];
            short4v s;
            #pragma unroll
            for (int j = 0; j < 4; ++j) s[j] = f2bs(rv[j] * hv[j]);
            *(short4v*)&rh[row * 520 + c4] = s;
        }
        __syncthreads();
        f32x4 acch = (f32x4){0.f,0.f,0.f,0.f};
        #pragma unroll
        for (int kf = 0; kf < 16; ++kf) {
            bf16x8 a = *(const bf16x8*)&rh[l15 * 520 + kf * 32 + quad * 8];
            acch = MFMA16(a, whh[kf], acch);
        }
        #pragma unroll
        for (int r = 0; r < 4; ++r) {
            int row = quad * 4 + r;
            int brow = c * 16 + row;
            int cc = col0 + l15;
            float x = acch[r] + bf2f(pre[((size_t)t * 128 + brow) * 1536 + 1024 + cc]);
            float e = __expf(-2.f * fabsf(x));
            float th = copysignf((1.f - e) / (1.f + e), x);
            float hd = hf[row * 512 + cc];
            hclu[row * 512 + cc] = (1.f - zloc[r]) * hd + zloc[r] * th;
        }
        __syncthreads();
        if (tid == 0) {
            __hip_atomic_fetch_add(ctrB, 1u, __ATOMIC_RELEASE, __HIP_MEMORY_SCOPE_AGENT);
            int guard = 0;
            while (__hip_atomic_load(ctrB, __ATOMIC_RELAXED, __HIP_MEMORY_SCOPE_AGENT) < tgt
                   && ++guard < (1 << 17))
                __builtin_amdgcn_s_sleep(1);
            __threadfence();
        }
        __syncthreads();
        // ---- phase C: gather h_new, write hseq, apply gamma(t+1) ----
        for (int i = tid; i < 16 * 128; i += 256) {
            int row = i >> 7, c4 = (i & 127) << 2;
            int brow = c * 16 + row;
            f32x4 hn = *(const f32x4*)&hclu[row * 512 + c4];
            if (w == 0) {
                short4v s;
                #pragma unroll
                for (int j = 0; j < 4; ++j) s[j] = f2bs(hn[j]);
                *(short4v*)&hseq[((size_t)t * 128 + brow) * 512 + c4] = s;
                if (t == CH - 1)
                    *(f32x4*)&hcarry[(size_t)brow * 512 + c4] = hn;
            }
            f32x4 hx;
            if (t < CH - 1) {
                ushort4v gv = *(const ushort4v*)&gammaf[((size_t)(t + 1) * 128 + brow) * 512 + c4];
                #pragma unroll
                for (int j = 0; j < 4; ++j) {
                    __half hh; *(unsigned short*)&hh = gv[j];
                    hx[j] = hn[j] * __half2float(hh);
                }
            } else hx = hn;
            *(f32x4*)&hf[row * 512 + c4] = hx;
            short4v sb;
            #pragma unroll
            for (int j = 0; j < 4; ++j) sb[j] = f2bs(hx[j]);
            *(short4v*)&hb[row * 520 + c4] = sb;
        }
        __syncthreads();
    }
}

// ---------------- launcher ----------------

extern "C" void kernel_launch(void* const* d_in, const int* in_sizes, int n_in,
                              void* d_out, int out_size, void* d_ws, size_t ws_size,
                              hipStream_t stream) {
    const float* C     = (const float*)d_in[0];
    const float* t_in  = (const float*)d_in[1];
    const int*   mask  = (const int*)d_in[2];
    const float* Wx    = (const float*)d_in[3];
    const float* Wh    = (const float*)d_in[4];
    const float* Wm    = (const float*)d_in[5];
    const float* bvec  = (const float*)d_in[6];
    const float* w_gx  = (const float*)d_in[7];
    const float* b_gx  = (const float*)d_in[8];
    const float* W_gh  = (const float*)d_in[9];
    const float* b_gh  = (const float*)d_in[10];
    const float* W_out = (const float*)d_in[11];
    const float* b_out = (const float*)d_in[12];

    char* w = (char*)d_ws;                              // total used: ~41.4 MB
    unsigned* ctr   = (unsigned*)(w + 0);               //   16384 (8 chunk slots)
    float* hcarry   = (float*)(w + 16384);              //  262144
    float* xmean    = (float*)(w + 278528);             //  262144
    float* xlastC   = (float*)(w + 540672);             //  262144
    float* dprevC   = (float*)(w + 802816);             //  262144
    float* mprevC   = (float*)(w + 1064960);            //  262144
    float* tprevC   = (float*)(w + 1327104);            //  262144
    bf16*  wcatT    = (bf16*)(w + 1589248);             // 3145728
    bf16*  wghT     = (bf16*)(w + 4734976);             //  524288
    bf16*  whT      = (bf16*)(w + 5259264);             // 1572864
    bf16*  woutT    = (bf16*)(w + 6832128);             //  262144
    bf16*  Xcat     = (bf16*)(w + 7094272);             //  8388608 (chunk)
    bf16*  Dbuf     = (bf16*)(w + 15482880);            //  4194304 (chunk)
    bf16*  pre      = (bf16*)(w + 19677184);            // 12582912 (chunk)
    __half* gamma   = (__half*)(w + 32260096);          //  4194304 (chunk)
    bf16*  hseq     = (bf16*)(w + 36454400);            //  4194304 (chunk)
    float* rbuf     = (float*)(w + 40648704);           //   524288
    float* hnbuf    = (float*)(w + 41173 *1024);        //   524288  (w+42161152... see note)

    // (fix hnbuf to a clean offset right after rbuf)
    hnbuf = (float*)(w + 40648704 + 524288);            //   524288 -> ends 41,697,280

    hipMemsetAsync(w, 0, 278528, stream);               // ctr + hcarry

    build_wcatT<<<6144, 256, 0, stream>>>(Wx, Wm, wcatT);
    transpose_f2b<<<1024, 256, 0, stream>>>(W_gh, wghT, 512, 512);
    transpose_f2b<<<3072, 256, 0, stream>>>(Wh, whT, 512, 1536);
    transpose_f2b<<<512, 256, 0, stream>>>(W_out, woutT, 512, 256);
    xmean_kernel<<<256, 256, 0, stream>>>(mask, C, xmean);

    for (int q = 0; q < NQ; ++q) {
        prep_kernel<<<256, 256, 0, stream>>>(mask, C, t_in, w_gx, b_gx, xmean,
                                             xlastC, dprevC, mprevC, tprevC,
                                             Xcat, Dbuf, q);
        gemm_bt<0><<<32 * 12, 256, 0, stream>>>(Xcat, wcatT, bvec, (void*)pre, 1536, 1024, q);
        gemm_bt<1><<<32 * 4, 256, 0, stream>>>(Dbuf, wghT, b_gh, (void*)gamma, 512, 512, q);
        scan_kernel<<<64, 256, 0, stream>>>(pre, gamma, whT, hseq, hcarry,
                                            rbuf, hnbuf, ctr + q * 512);
        gemm_bt<2><<<32 * 2, 256, 0, stream>>>(hseq, woutT, b_out, d_out, 256, 512, q);
    }
}